// Round 6
// baseline (445.476 us; speedup 1.0000x reference)
//
#include <hip/hip_runtime.h>

#define IN_F 128
#define OUT_F 32

typedef unsigned int uint32;

// bf16 (in low 16 bits) -> f32
__device__ __forceinline__ float bf2f(uint32 u) {
    union { uint32 ui; float f; } c; c.ui = u << 16; return c.f;
}
// f32 -> bf16 bits, RNE
__device__ __forceinline__ uint32 f2bf(float x) {
    union { float f; uint32 ui; } c; c.f = x;
    uint32 u = c.ui;
    u += 0x7fffu + ((u >> 16) & 1u);
    return u >> 16;
}

// ---- degree histogram ---------------------------------------------------
__global__ void k_hist(const int* __restrict__ dst, int* __restrict__ cnt, int E) {
    int e = blockIdx.x * blockDim.x + threadIdx.x;
    if (e < E) atomicAdd(&cnt[dst[e]], 1);
}

// ---- fused gemm: h = x@W^T ; d = rsqrt(deg) ;
//      gbf = bf16(h*d) ; out = d*d*h + b ; dis[node] = d -----------------
// block = 256 threads; 32 nodes/block; 8 f-groups x 4 nodes/thread
__global__ void __launch_bounds__(256) k_gemm(
        const float* __restrict__ x, const float* __restrict__ W,
        const int* __restrict__ cnt, const float* __restrict__ b,
        unsigned short* __restrict__ gbf, float* __restrict__ out,
        float* __restrict__ dis, int n) {
    __shared__ float  Wl[OUT_F * 132];   // [f][k], f-row stride 132 dwords (pad)
    __shared__ float4 xl4[32 * 32];      // [row][k4]

    int tid = threadIdx.x;

    // stage W: 4096 floats, conflict-free (consecutive k -> consecutive banks)
    #pragma unroll
    for (int it = 0; it < 16; ++it) {
        int j = it * 256 + tid;
        Wl[(j >> 7) * 132 + (j & 127)] = W[j];
    }
    // stage x: 1024 float4, coalesced global, 2-way LDS write (free)
    int nodeBase = blockIdx.x * 32;
    #pragma unroll
    for (int it = 0; it < 4; ++it) {
        int slot = it * 256 + tid;
        int row = slot >> 5, c4 = slot & 31;
        int nrow = nodeBase + row;
        if (nrow < n) xl4[slot] = ((const float4*)x)[nrow * 32 + c4];
    }
    __syncthreads();

    int f = tid & 31, q = tid >> 5;
    const float4* Wf = (const float4*)&Wl[f * 132];  // 132*4B = 528B, 16B-aligned
    const float4* xr = &xl4[(q * 4) * 32];

    float acc0 = 0.f, acc1 = 0.f, acc2 = 0.f, acc3 = 0.f;
    #pragma unroll
    for (int k4 = 0; k4 < 32; ++k4) {
        float4 wv = Wf[k4];            // b128, distinct per f, bank-uniform
        float4 a0 = xr[k4];            // b128 broadcast (2 addrs/wave = free)
        float4 a1 = xr[32 + k4];
        float4 a2 = xr[64 + k4];
        float4 a3 = xr[96 + k4];
        acc0 = fmaf(a0.x, wv.x, acc0); acc0 = fmaf(a0.y, wv.y, acc0);
        acc0 = fmaf(a0.z, wv.z, acc0); acc0 = fmaf(a0.w, wv.w, acc0);
        acc1 = fmaf(a1.x, wv.x, acc1); acc1 = fmaf(a1.y, wv.y, acc1);
        acc1 = fmaf(a1.z, wv.z, acc1); acc1 = fmaf(a1.w, wv.w, acc1);
        acc2 = fmaf(a2.x, wv.x, acc2); acc2 = fmaf(a2.y, wv.y, acc2);
        acc2 = fmaf(a2.z, wv.z, acc2); acc2 = fmaf(a2.w, wv.w, acc2);
        acc3 = fmaf(a3.x, wv.x, acc3); acc3 = fmaf(a3.y, wv.y, acc3);
        acc3 = fmaf(a3.z, wv.z, acc3); acc3 = fmaf(a3.w, wv.w, acc3);
    }

    float accs[4] = {acc0, acc1, acc2, acc3};
    int n0 = nodeBase + q * 4;
    #pragma unroll
    for (int r = 0; r < 4; ++r) {
        int node = n0 + r;
        if (node < n) {
            float d = rsqrtf((float)(cnt[node] + 1));
            float g = accs[r] * d;
            gbf[node * OUT_F + f] = (unsigned short)f2bf(g);
            out[node * OUT_F + f] = d * g + b[f];
            if (f == 0) dis[node] = d;
        }
    }
}

// ---- scatter: accbf2[d*16+l] += bf16x2( g2[s*16+l] * dis[d] ) -----------
// 16 lanes per edge, 2 independent edges per thread (ILP)
__global__ void k_scatter(const uint32* __restrict__ g2, const int* __restrict__ src,
                          const int* __restrict__ dst, const float* __restrict__ dis,
                          uint32* __restrict__ acc2, int Ehalf) {
    long long t = (long long)blockIdx.x * blockDim.x + threadIdx.x;
    int e0 = (int)(t >> 4);
    if (e0 >= Ehalf) return;
    int l  = (int)(t & 15);
    int e1 = e0 + Ehalf;

    int s0 = src[e0], d0 = dst[e0];
    int s1 = src[e1], d1 = dst[e1];
    uint32 v0 = g2[s0 * 16 + l];
    uint32 v1 = g2[s1 * 16 + l];
    float w0 = dis[d0];
    float w1 = dis[d1];

    uint32 p0 = f2bf(bf2f(v0 & 0xffffu) * w0) | (f2bf(bf2f(v0 >> 16) * w0) << 16);
    uint32 p1 = f2bf(bf2f(v1 & 0xffffu) * w1) | (f2bf(bf2f(v1 >> 16) * w1) << 16);

    uint32* a0 = acc2 + (d0 * 16 + l);
    uint32* a1 = acc2 + (d1 * 16 + l);
    asm volatile("global_atomic_pk_add_bf16 %0, %1, off" :: "v"(a0), "v"(p0) : "memory");
    asm volatile("global_atomic_pk_add_bf16 %0, %1, off" :: "v"(a1), "v"(p1) : "memory");
}

// ---- final: out += f32(accbf) -------------------------------------------
__global__ void k_final(const uint32* __restrict__ acc2, float2* __restrict__ out2, int n16) {
    int i = blockIdx.x * blockDim.x + threadIdx.x;
    if (i < n16) {
        uint32 a = acc2[i];
        float2 o = out2[i];
        o.x += bf2f(a & 0xffffu);
        o.y += bf2f(a >> 16);
        out2[i] = o;
    }
}

extern "C" void kernel_launch(void* const* d_in, const int* in_sizes, int n_in,
                              void* d_out, int out_size, void* d_ws, size_t ws_size,
                              hipStream_t stream) {
    const float* x  = (const float*)d_in[0];
    const int*   ei = (const int*)d_in[1];
    const float* W  = (const float*)d_in[2];
    const float* b  = (const float*)d_in[3];
    float* out = (float*)d_out;

    int N = in_sizes[0] / IN_F;   // 100000
    int E = in_sizes[1] / 2;      // 1600000
    const int* src = ei;
    const int* dst = ei + E;

    // workspace: [cnt: N ints][accbf: N*32 bf16][gbf: N*32 bf16][dis: N f32]
    char* p = (char*)d_ws;
    int*            cnt  = (int*)p;            p += (size_t)N * 4;
    uint32*         acc2 = (uint32*)p;         p += (size_t)N * OUT_F * 2;
    unsigned short* gbf  = (unsigned short*)p; p += (size_t)N * OUT_F * 2;
    float*          dis  = (float*)p;          p += (size_t)N * 4;

    // zero cnt + accbf in one shot (adjacent)
    (void)hipMemsetAsync(cnt, 0, (size_t)N * 4 + (size_t)N * OUT_F * 2, stream);

    k_hist<<<(E + 255) / 256, 256, 0, stream>>>(dst, cnt, E);
    k_gemm<<<(N + 31) / 32, 256, 0, stream>>>(x, W, cnt, b, gbf, out, dis, N);

    int Ehalf = E / 2;
    long long tasks = (long long)Ehalf * 16;
    k_scatter<<<(int)((tasks + 255) / 256), 256, 0, stream>>>(
        (const uint32*)gbf, src, dst, dis, acc2, Ehalf);

    int n16 = N * 16;
    k_final<<<(n16 + 255) / 256, 256, 0, stream>>>(acc2, (float2*)out, n16);
}

// Round 7
// 270.345 us; speedup vs baseline: 1.6478x; 1.6478x over previous
//
#include <hip/hip_runtime.h>

#define IN_F 128
#define OUT_F 32

typedef unsigned int uint32;

// bf16 (in low 16 bits) -> f32
__device__ __forceinline__ float bf2f(uint32 u) {
    union { uint32 ui; float f; } c; c.ui = u << 16; return c.f;
}
// f32 -> bf16 bits, RNE
__device__ __forceinline__ uint32 f2bf(float x) {
    union { float f; uint32 ui; } c; c.f = x;
    uint32 u = c.ui;
    u += 0x7fffu + ((u >> 16) & 1u);
    return u >> 16;
}

// ---- degree histogram ---------------------------------------------------
__global__ void k_hist(const int* __restrict__ dst, int* __restrict__ cnt, int E) {
    int e = blockIdx.x * blockDim.x + threadIdx.x;
    if (e < E) atomicAdd(&cnt[dst[e]], 1);
}

// ---- fused gemm: h = x@W^T ; d = rsqrt(deg) ;
//      gbf = bf16(h*d) ; out = d*d*h + b ; dis[node] = d -----------------
// block = 256 threads; 16 nodes/block; 8 q-groups x 2 nodes/thread
__global__ void __launch_bounds__(256) k_gemm(
        const float* __restrict__ x, const float* __restrict__ W,
        const int* __restrict__ cnt, const float* __restrict__ b,
        unsigned short* __restrict__ gbf, float* __restrict__ out,
        float* __restrict__ dis, int n) {
    __shared__ float  Wl[OUT_F * 132];   // [f][k], f-row stride 132 dwords (pad)
    __shared__ float4 xl4[16 * 32];      // [row][k4]

    int tid = threadIdx.x;

    // stage W: 4096 floats, conflict-free (consecutive k -> consecutive banks)
    #pragma unroll
    for (int it = 0; it < 16; ++it) {
        int j = it * 256 + tid;
        Wl[(j >> 7) * 132 + (j & 127)] = W[j];
    }
    // stage x: 512 float4, coalesced global, consecutive LDS slots
    int nodeBase = blockIdx.x * 16;
    #pragma unroll
    for (int it = 0; it < 2; ++it) {
        int slot = it * 256 + tid;
        int row = slot >> 5, c4 = slot & 31;
        int nrow = nodeBase + row;
        if (nrow < n) xl4[slot] = ((const float4*)x)[nrow * 32 + c4];
    }
    __syncthreads();

    int f = tid & 31, q = tid >> 5;
    const float4* Wf = (const float4*)&Wl[f * 132];  // 528B stride, 16B-aligned
    const float4* xr = &xl4[(q * 2) * 32];

    float acc0 = 0.f, acc1 = 0.f;
    #pragma unroll 4
    for (int k4 = 0; k4 < 32; ++k4) {
        float4 wv = Wf[k4];            // b128, distinct per f, bank-spread
        float4 a0 = xr[k4];            // b128 broadcast (2 addrs/wave)
        float4 a1 = xr[32 + k4];
        acc0 = fmaf(a0.x, wv.x, acc0); acc0 = fmaf(a0.y, wv.y, acc0);
        acc0 = fmaf(a0.z, wv.z, acc0); acc0 = fmaf(a0.w, wv.w, acc0);
        acc1 = fmaf(a1.x, wv.x, acc1); acc1 = fmaf(a1.y, wv.y, acc1);
        acc1 = fmaf(a1.z, wv.z, acc1); acc1 = fmaf(a1.w, wv.w, acc1);
    }

    float accs[2] = {acc0, acc1};
    int n0 = nodeBase + q * 2;
    #pragma unroll
    for (int r = 0; r < 2; ++r) {
        int node = n0 + r;
        if (node < n) {
            float d = rsqrtf((float)(cnt[node] + 1));
            float g = accs[r] * d;
            gbf[node * OUT_F + f] = (unsigned short)f2bf(g);
            out[node * OUT_F + f] = d * g + b[f];
            if (f == 0) dis[node] = d;
        }
    }
}

// ---- scatter: accbf2[d*16+l] += bf16x2( g2[s*16+l] * dis[d] ) -----------
// 16 lanes per edge, 2 independent edges per thread (ILP)
__global__ void k_scatter(const uint32* __restrict__ g2, const int* __restrict__ src,
                          const int* __restrict__ dst, const float* __restrict__ dis,
                          uint32* __restrict__ acc2, int Ehalf) {
    long long t = (long long)blockIdx.x * blockDim.x + threadIdx.x;
    int e0 = (int)(t >> 4);
    if (e0 >= Ehalf) return;
    int l  = (int)(t & 15);
    int e1 = e0 + Ehalf;

    int s0 = src[e0], d0 = dst[e0];
    int s1 = src[e1], d1 = dst[e1];
    uint32 v0 = g2[s0 * 16 + l];
    uint32 v1 = g2[s1 * 16 + l];
    float w0 = dis[d0];
    float w1 = dis[d1];

    uint32 p0 = f2bf(bf2f(v0 & 0xffffu) * w0) | (f2bf(bf2f(v0 >> 16) * w0) << 16);
    uint32 p1 = f2bf(bf2f(v1 & 0xffffu) * w1) | (f2bf(bf2f(v1 >> 16) * w1) << 16);

    uint32* a0 = acc2 + (d0 * 16 + l);
    uint32* a1 = acc2 + (d1 * 16 + l);
    asm volatile("global_atomic_pk_add_bf16 %0, %1, off" :: "v"(a0), "v"(p0) : "memory");
    asm volatile("global_atomic_pk_add_bf16 %0, %1, off" :: "v"(a1), "v"(p1) : "memory");
}

// ---- final: out += f32(accbf) -------------------------------------------
__global__ void k_final(const uint32* __restrict__ acc2, float2* __restrict__ out2, int n16) {
    int i = blockIdx.x * blockDim.x + threadIdx.x;
    if (i < n16) {
        uint32 a = acc2[i];
        float2 o = out2[i];
        o.x += bf2f(a & 0xffffu);
        o.y += bf2f(a >> 16);
        out2[i] = o;
    }
}

extern "C" void kernel_launch(void* const* d_in, const int* in_sizes, int n_in,
                              void* d_out, int out_size, void* d_ws, size_t ws_size,
                              hipStream_t stream) {
    const float* x  = (const float*)d_in[0];
    const int*   ei = (const int*)d_in[1];
    const float* W  = (const float*)d_in[2];
    const float* b  = (const float*)d_in[3];
    float* out = (float*)d_out;

    int N = in_sizes[0] / IN_F;   // 100000
    int E = in_sizes[1] / 2;      // 1600000
    const int* src = ei;
    const int* dst = ei + E;

    // workspace: [cnt: N ints][accbf: N*32 bf16][gbf: N*32 bf16][dis: N f32]
    char* p = (char*)d_ws;
    int*            cnt  = (int*)p;            p += (size_t)N * 4;
    uint32*         acc2 = (uint32*)p;         p += (size_t)N * OUT_F * 2;
    unsigned short* gbf  = (unsigned short*)p; p += (size_t)N * OUT_F * 2;
    float*          dis  = (float*)p;          p += (size_t)N * 4;

    // zero cnt + accbf in one shot (adjacent)
    (void)hipMemsetAsync(cnt, 0, (size_t)N * 4 + (size_t)N * OUT_F * 2, stream);

    k_hist<<<(E + 255) / 256, 256, 0, stream>>>(dst, cnt, E);
    k_gemm<<<(N + 15) / 16, 256, 0, stream>>>(x, W, cnt, b, gbf, out, dis, N);

    int Ehalf = E / 2;
    long long tasks = (long long)Ehalf * 16;
    k_scatter<<<(int)((tasks + 255) / 256), 256, 0, stream>>>(
        (const uint32*)gbf, src, dst, dis, acc2, Ehalf);

    int n16 = N * 16;
    k_final<<<(n16 + 255) / 256, 256, 0, stream>>>(acc2, (float2*)out, n16);
}